// Round 15
// baseline (162.823 us; speedup 1.0000x reference)
//
#include <hip/hip_runtime.h>
#include <math.h>

// STRNN: B=16, S=128, D=64, K=64, H=128, NSLOT+1=97 slots.
//
// Pipeline:
//  k_hist1    : per-block LDS histograms (128 blocks x 2048 elems = 16 rows/block)
//  k_scan_all : ONE combined exclusive scan over BH_T++BH_D + small (b,i) scan
//  k_scatter  : one pass; LDS cursors; emits t-sorted entries, d-sorted refs, Y slots
//  k_phaseA   : per t-bucket GEMM xt = x[b,j] @ Tw[t] (VALU f32) -> XT f16 [tpos][64]
//  k_phaseB   : per d-bucket GEMM y = xt @ Dw[d] via MFMA f16 -> Y f16 [dstpos][128]
//  k_reduce   : XC[b,i,:] = f32 sum of its contiguous Y f16 rows
//  k_recur    : MFMA recurrence: ONE block (8 waves), per step
//               Y[16x128] = h[16x128] @ Wh[128x128] via mfma_f32_16x16x32_f16;
//               Wh B-frags in VGPRs (one-time), h in 9KB LDS dbuf, XC prefetch 4 deep.
//
// ws requirement: ~54 MB for the atomic-free path (guarded; fallback = atomicAdd XC).

#define B_ 16
#define S_ 128
#define D_ 64
#define K_ 64
#define H_ 128
#define NS 97
#define NB 128       // histogram blocks; 2048 elems (16 rows) each
#define MAXE 132096  // B * S*(S+1)/2  (upper bound on valid triples)

// u32-index offsets into ws
#define XC_OFF 0                   // f32 [2048][128]
#define BH_T   262144              // u32 [97][128]
#define BH_D   (BH_T + NS * NB)    // u32 [97][128]  (contiguous after BH_T!)
#define CNT_T  (BH_D + NS * NB)    // u32 [97]
#define CNT_D  (CNT_T + NS)        // u32 [97]
#define CNT_B  (CNT_D + NS)        // u32 [2048]
#define OFF_T  (CNT_B + 2048)      // u32 [98]
#define OFF_D  (OFF_T + 98)        // u32 [98]
#define OFF_B  (OFF_D + 98)        // u32 [2049]
#define ENT_T  291464              // u32 [MAXE]  (16B aligned)
#define ENT_DX (ENT_T + MAXE)      // u32 [MAXE] xt-row index (t-sorted pos)
#define ENT_DP (ENT_DX + MAXE)     // u32 [MAXE] Y-row (dst-sorted pos) [or dst in fallback]
#define XT16_OFF (ENT_DP + MAXE)   // f16 [MAXE][64]  (MAXE*32 u32)
#define Y16_OFF  (XT16_OFF + MAXE * 32)  // f16 [MAXE][128] (MAXE*64 u32)
#define NEED_BYTES ((size_t)(Y16_OFF + (size_t)MAXE * 64) * 4)

typedef _Float16 f16x8 __attribute__((ext_vector_type(8)));
typedef float f32x4 __attribute__((ext_vector_type(4)));

// ---- binning: 128 blocks x 2048 elements (16 (b,i) rows per block) ----

__global__ __launch_bounds__(256) void k_hist1(const int* __restrict__ tc,
                                               const int* __restrict__ dc,
                                               const int* __restrict__ mk,
                                               unsigned* wsi) {
    __shared__ unsigned ht[NS], hd[NS], hb[16];
    int tid = threadIdx.x, blk = blockIdx.x;
    if (tid < NS) { ht[tid] = 0; hd[tid] = 0; }
    if (tid < 16) hb[tid] = 0;
    __syncthreads();
    int base = blk * 2048;
    #pragma unroll
    for (int u = 0; u < 8; u++) {
        int idx = base + tid + u * 256;
        int i = (idx >> 7) & 127, j = idx & 127;
        if (j <= i && mk[idx] != 0) {
            atomicAdd(&ht[tc[idx]], 1u);
            atomicAdd(&hd[dc[idx]], 1u);
            atomicAdd(&hb[(idx >> 7) & 15], 1u);
        }
    }
    __syncthreads();
    if (tid < NS) {
        wsi[BH_T + tid * NB + blk] = ht[tid];
        wsi[BH_D + tid * NB + blk] = hd[tid];
    }
    if (tid < 16) wsi[CNT_B + blk * 16 + tid] = hb[tid];
}

template <int CH>
__device__ unsigned scan_region(unsigned* in, unsigned* out, int L, unsigned* s) {
    int tid = threadIdx.x;
    unsigned loc[CH], sum = 0;
    #pragma unroll
    for (int k = 0; k < CH; k++) {
        int idx = tid * CH + k;
        loc[k] = (idx < L) ? in[idx] : 0u;
        sum += loc[k];
    }
    s[tid] = sum;
    __syncthreads();
    for (int o = 1; o < 1024; o <<= 1) {
        unsigned a = (tid >= o) ? s[tid - o] : 0u;
        __syncthreads();
        s[tid] += a;
        __syncthreads();
    }
    unsigned total = s[1023];
    unsigned run = s[tid] - sum;
    __syncthreads();
    #pragma unroll
    for (int k = 0; k < CH; k++) {
        int idx = tid * CH + k;
        if (idx < L) { out[idx] = run; run += loc[k]; }
    }
    __syncthreads();
    return total;
}

__global__ __launch_bounds__(1024) void k_scan_all(unsigned* wsi) {
    __shared__ unsigned s[1024];
    int tid = threadIdx.x;

    // ONE combined scan over BH_T ++ BH_D (contiguous, 2*NS*NB = 24832 <= 1024*25)
    unsigned tot = scan_region<25>(wsi + BH_T, wsi + BH_T, 2 * NS * NB, s);
    unsigned totT = wsi[BH_D];          // exclusive prefix at start of D part == totT
    if (tid < NS) {
        unsigned b0 = wsi[BH_T + tid * NB];
        unsigned b1 = (tid < NS - 1) ? wsi[BH_T + (tid + 1) * NB] : totT;
        wsi[OFF_T + tid] = b0;
        wsi[CNT_T + tid] = b1 - b0;
        unsigned d0 = wsi[BH_D + tid * NB];
        unsigned d1 = (tid < NS - 1) ? wsi[BH_D + (tid + 1) * NB] : tot;
        wsi[OFF_D + tid] = d0 - totT;
        wsi[CNT_D + tid] = d1 - d0;
    }
    if (tid == 0) { wsi[OFF_T + NS] = totT; wsi[OFF_D + NS] = tot - totT; }
    __syncthreads();

    unsigned totB = scan_region<2>(wsi + CNT_B, wsi + OFF_B, 2048, s);
    if (tid == 0) wsi[OFF_B + 2048] = totB;
}

__global__ __launch_bounds__(256) void k_scatter(const int* __restrict__ tc,
                                                 const int* __restrict__ dc,
                                                 const int* __restrict__ mk,
                                                 unsigned* wsi, int useY) {
    __shared__ unsigned ct[NS], cd[NS], cb[16];
    int tid = threadIdx.x, blk = blockIdx.x;
    unsigned totT = wsi[OFF_T + NS];    // D-part bases are shifted by totT
    if (tid < NS) {
        ct[tid] = wsi[BH_T + tid * NB + blk];
        cd[tid] = wsi[BH_D + tid * NB + blk] - totT;
    }
    if (tid < 16) cb[tid] = wsi[OFF_B + blk * 16 + tid];
    __syncthreads();
    int base = blk * 2048;
    #pragma unroll
    for (int u = 0; u < 8; u++) {
        int idx = base + tid + u * 256;
        int i = (idx >> 7) & 127, j = idx & 127, b = idx >> 14;
        if (j <= i && mk[idx] != 0) {
            unsigned t = (unsigned)tc[idx], d = (unsigned)dc[idx];
            unsigned tpos = atomicAdd(&ct[t], 1u);
            wsi[ENT_T + tpos] = (unsigned)b | ((unsigned)i << 4) | ((unsigned)j << 11)
                              | (t << 18) | (d << 25);
            unsigned dpos = atomicAdd(&cd[d], 1u);
            unsigned yp = useY ? atomicAdd(&cb[(idx >> 7) & 15], 1u) : (unsigned)(idx >> 7);
            wsi[ENT_DX + dpos] = tpos;
            wsi[ENT_DP + dpos] = yp;
        }
    }
}

// phase A (VALU f32, r12-proven): xt[entry][kk] = sum_dd x[b,j][dd]*Tw[t][dd][kk];
// XT stored as f16.
__global__ __launch_bounds__(256) void k_phaseA(const float* __restrict__ x,
                                                const float* __restrict__ tw,
                                                unsigned* wsi, float* wsf) {
    int t = blockIdx.x, c = blockIdx.y;
    int rows = (int)wsi[CNT_T + t] - c * 128;
    if (rows <= 0) return;
    if (rows > 128) rows = 128;
    unsigned base = wsi[OFF_T + t] + c * 128;

    __shared__ float stw[4096];     // Tw[t] row-major [dd][kk]
    __shared__ float sx[8192];      // x rows, XOR-swizzled in 4-float units
    __shared__ unsigned ent[128];
    int tid = threadIdx.x;

    const float4* twg = (const float4*)(tw + t * 4096);
    float4* stw4 = (float4*)stw;
    #pragma unroll
    for (int q = 0; q < 4; q++) stw4[q * 256 + tid] = twg[q * 256 + tid];
    if (tid < 128) ent[tid] = (tid < rows) ? wsi[ENT_T + base + tid] : 0u;
    __syncthreads();

    int lane16 = tid & 15, rquot = tid >> 4;
    #pragma unroll
    for (int p = 0; p < 8; p++) {
        int r = p * 16 + rquot;
        float4 v = make_float4(0.f, 0.f, 0.f, 0.f);
        if (r < rows) {
            unsigned e = ent[r];
            int b = e & 15, j = (e >> 11) & 127;
            v = *(const float4*)(x + (b * S_ + j) * D_ + lane16 * 4);
        }
        int col4 = lane16 ^ (r & 15);
        float* dst = &sx[r * 64 + col4 * 4];
        dst[0] = v.x; dst[1] = v.y; dst[2] = v.z; dst[3] = v.w;
    }
    __syncthreads();

    int rgrp = tid & 15, cgrp = tid >> 4;   // 8 rows (rgrp+16i) x 4 cols (cgrp*4..)
    float4 acc[8];
    #pragma unroll
    for (int i = 0; i < 8; i++) acc[i] = make_float4(0.f, 0.f, 0.f, 0.f);
    #pragma unroll 4
    for (int dd = 0; dd < 64; dd++) {
        float4 w = stw4[dd * 16 + cgrp];
        int s_idx = (((dd >> 2) ^ rgrp) << 2) + (dd & 3);
        #pragma unroll
        for (int i = 0; i < 8; i++) {
            float a = sx[(rgrp + 16 * i) * 64 + s_idx];
            acc[i].x += a * w.x; acc[i].y += a * w.y;
            acc[i].z += a * w.z; acc[i].w += a * w.w;
        }
    }
    _Float16* XT = (_Float16*)(wsf + XT16_OFF);
    #pragma unroll
    for (int i = 0; i < 8; i++) {
        int r = rgrp + 16 * i;
        if (r < rows) {
            union { _Float16 h[4]; double d64; } u;
            u.h[0] = (_Float16)acc[i].x; u.h[1] = (_Float16)acc[i].y;
            u.h[2] = (_Float16)acc[i].z; u.h[3] = (_Float16)acc[i].w;
            *(double*)&XT[(size_t)(base + r) * 64 + cgrp * 4] = u.d64;
        }
    }
}

// phase B (MFMA f16): y[rows x 128] = XT16-rows[rows x 64] @ Dw[d][64 x 128] -> Y f16.
__global__ __launch_bounds__(256) void k_phaseB(const float* __restrict__ dw,
                                                unsigned* wsi, float* wsf, int useY) {
    int d = blockIdx.x, c = blockIdx.y;
    int rows = (int)wsi[CNT_D + d] - c * 128;
    if (rows <= 0) return;
    if (rows > 128) rows = 128;
    unsigned base = wsi[OFF_D + d] + c * 128;

    __shared__ _Float16 sa[128 * 64];     // A: XT rows f16, chunk-swizzled (16 KB)
    __shared__ _Float16 sb[64 * 128];     // B: Dw f16 [k][h] linear (16 KB)
    __shared__ unsigned entx_s[128], entp_s[128];
    int tid = threadIdx.x;

    if (tid < 128) {
        entx_s[tid] = (tid < rows) ? wsi[ENT_DX + base + tid] : 0u;
        entp_s[tid] = (tid < rows) ? wsi[ENT_DP + base + tid] : 0u;
    }
    const float4* dwg = (const float4*)(dw + (size_t)d * 8192);
    #pragma unroll
    for (int q = 0; q < 8; q++) {
        float4 v = dwg[q * 256 + tid];
        union { _Float16 h[4]; double d64; } u;
        u.h[0] = (_Float16)v.x; u.h[1] = (_Float16)v.y;
        u.h[2] = (_Float16)v.z; u.h[3] = (_Float16)v.w;
        *(double*)&sb[(q * 256 + tid) * 4] = u.d64;
    }
    __syncthreads();

    {
        int r = tid >> 1, hh = tid & 1;
        const _Float16* XT = (const _Float16*)(wsf + XT16_OFF);
        const f16x8* src = (const f16x8*)(XT + (size_t)entx_s[r] * 64 + hh * 32);
        #pragma unroll
        for (int mm = 0; mm < 4; mm++) {
            f16x8 hv = {0, 0, 0, 0, 0, 0, 0, 0};
            if (r < rows) hv = src[mm];
            int chunk = hh * 4 + mm;
            *(f16x8*)&sa[r * 64 + (chunk ^ (r & 7)) * 8] = hv;
        }
    }
    __syncthreads();

    int w = tid >> 6, lane = tid & 63;
    int l15 = lane & 15, lg = lane >> 4;
    f16x8 bf[2][2];
    #pragma unroll
    for (int n = 0; n < 2; n++) {
        int col = w * 32 + n * 16 + l15;
        #pragma unroll
        for (int ks = 0; ks < 2; ks++) {
            int kb = ks * 32 + lg * 8;
            f16x8 t;
            #pragma unroll
            for (int e = 0; e < 8; e++) t[e] = sb[(kb + e) * 128 + col];
            bf[n][ks] = t;
        }
    }
    f32x4 acc[8][2];
    f32x4 z = {0.f, 0.f, 0.f, 0.f};
    #pragma unroll
    for (int m = 0; m < 8; m++) { acc[m][0] = z; acc[m][1] = z; }

    #pragma unroll
    for (int m = 0; m < 8; m++) {
        int row = m * 16 + l15;
        f16x8 a0 = *(f16x8*)&sa[row * 64 + ((lg) ^ (row & 7)) * 8];
        f16x8 a1 = *(f16x8*)&sa[row * 64 + ((4 + lg) ^ (row & 7)) * 8];
        #pragma unroll
        for (int n = 0; n < 2; n++) {
            acc[m][n] = __builtin_amdgcn_mfma_f32_16x16x32_f16(a0, bf[n][0], acc[m][n], 0, 0, 0);
            acc[m][n] = __builtin_amdgcn_mfma_f32_16x16x32_f16(a1, bf[n][1], acc[m][n], 0, 0, 0);
        }
    }

    if (useY) {
        _Float16* Y16 = (_Float16*)(wsf + Y16_OFF);
        #pragma unroll
        for (int m = 0; m < 8; m++) {
            #pragma unroll
            for (int reg = 0; reg < 4; reg++) {
                int row = m * 16 + lg * 4 + reg;
                if (row < rows) {
                    _Float16* p = Y16 + (size_t)entp_s[row] * 128 + w * 32 + l15;
                    p[0]  = (_Float16)acc[m][0][reg];
                    p[16] = (_Float16)acc[m][1][reg];
                }
            }
        }
    } else {
        float* XC = wsf + XC_OFF;
        #pragma unroll
        for (int m = 0; m < 8; m++) {
            #pragma unroll
            for (int reg = 0; reg < 4; reg++) {
                int row = m * 16 + lg * 4 + reg;
                if (row < rows) {
                    float* p = XC + (size_t)entp_s[row] * 128 + w * 32 + l15;
                    atomicAdd(p + 0,  acc[m][0][reg]);
                    atomicAdd(p + 16, acc[m][1][reg]);
                }
            }
        }
    }
}

// XC[b,i,:] = f32 sum of this (b,i)'s contiguous Y16 rows
__global__ __launch_bounds__(128) void k_reduce(unsigned* wsi, float* wsf) {
    int bi = blockIdx.x, tid = threadIdx.x;
    unsigned n = wsi[CNT_B + bi], off = wsi[OFF_B + bi];
    const _Float16* Yp = (const _Float16*)(wsf + Y16_OFF) + (size_t)off * 128 + tid;
    float a0 = 0.f, a1 = 0.f, a2 = 0.f, a3 = 0.f;
    unsigned e = 0;
    for (; e + 4 <= n; e += 4) {
        a0 += (float)Yp[(size_t)e * 128];
        a1 += (float)Yp[(size_t)(e + 1) * 128];
        a2 += (float)Yp[(size_t)(e + 2) * 128];
        a3 += (float)Yp[(size_t)(e + 3) * 128];
    }
    for (; e < n; e++) a0 += (float)Yp[(size_t)e * 128];
    wsf[XC_OFF + (size_t)bi * 128 + tid] = (a0 + a1) + (a2 + a3);
}

// MFMA recurrence: ONE block, 512 threads = 8 waves; wave wv owns col strip
// [wv*16, wv*16+16). Per step i: Y[16x128] = h[16x128] @ Wh[128x128] as one
// 16x16x32 MFMA per wave per K-step (4 K-steps, chained into one f32x4 acc).
// Wh B-frags live in VGPRs (loaded once via LDS-staged f16); h lives in a
// double-buffered LDS [16][136] f16 (272B row stride, 16B-aligned, bank-spread).
// A-frag: row = lane&15 (batch), k = ks*32 + (lane>>4)*8 + e  [phaseB-validated].
// C/D:    col = lane&15, row(batch) = (lane>>4)*4 + reg        [m89-verified].
// XC prefetched 4 steps deep in named float4 registers. One barrier per step.
#define LD_XC(V, I)                                                            \
    { V.x = XCp[0 * 16384 + (I) * 128]; V.y = XCp[1 * 16384 + (I) * 128];      \
      V.z = XCp[2 * 16384 + (I) * 128]; V.w = XCp[3 * 16384 + (I) * 128]; }

#define QSTEP(XCR, IDX, CUR)                                                   \
    {                                                                          \
        const _Float16* hbp = &hbuf[CUR][(size_t)l15 * 136];                   \
        f16x8 a0 = *(const f16x8*)&hbp[lg * 8];                                \
        f16x8 a1 = *(const f16x8*)&hbp[32 + lg * 8];                           \
        f16x8 a2 = *(const f16x8*)&hbp[64 + lg * 8];                           \
        f16x8 a3 = *(const f16x8*)&hbp[96 + lg * 8];                           \
        f32x4 acc = {0.f, 0.f, 0.f, 0.f};                                      \
        acc = __builtin_amdgcn_mfma_f32_16x16x32_f16(a0, bf[0], acc, 0, 0, 0); \
        acc = __builtin_amdgcn_mfma_f32_16x16x32_f16(a1, bf[1], acc, 0, 0, 0); \
        acc = __builtin_amdgcn_mfma_f32_16x16x32_f16(a2, bf[2], acc, 0, 0, 0); \
        acc = __builtin_amdgcn_mfma_f32_16x16x32_f16(a3, bf[3], acc, 0, 0, 0); \
        float4 xcu = XCR;                                                      \
        if (i + 4 + (IDX) < 128) LD_XC(XCR, i + 4 + (IDX));                    \
        float v0 = 1.f / (1.f + __expf(-(xcu.x + acc[0])));                    \
        float v1 = 1.f / (1.f + __expf(-(xcu.y + acc[1])));                    \
        float v2 = 1.f / (1.f + __expf(-(xcu.z + acc[2])));                    \
        float v3 = 1.f / (1.f + __expf(-(xcu.w + acc[3])));                    \
        _Float16* hn = &hbuf[(CUR) ^ 1][0];                                    \
        hn[(lg * 4 + 0) * 136 + col] = (_Float16)v0;                           \
        hn[(lg * 4 + 1) * 136 + col] = (_Float16)v1;                           \
        hn[(lg * 4 + 2) * 136 + col] = (_Float16)v2;                           \
        hn[(lg * 4 + 3) * 136 + col] = (_Float16)v3;                           \
        float* op = out + (size_t)(i + (IDX)) * 128 + col;                     \
        op[(size_t)(lg * 4 + 0) * 16384] = v0;                                 \
        op[(size_t)(lg * 4 + 1) * 16384] = v1;                                 \
        op[(size_t)(lg * 4 + 2) * 16384] = v2;                                 \
        op[(size_t)(lg * 4 + 3) * 16384] = v3;                                 \
        lastv = make_float4(v0, v1, v2, v3);                                   \
        __syncthreads();                                                       \
    }

__global__ __launch_bounds__(512) void k_recur(const float* __restrict__ hw,
                                               const float* __restrict__ wsf,
                                               float* __restrict__ out) {
    __shared__ _Float16 sb[128 * 128];      // Wh f16 [k][col] linear (32 KB, one-time)
    __shared__ _Float16 hbuf[2][16 * 136];  // h dbuf, 272B row stride (~8.7 KB)
    int tid = threadIdx.x;
    int wv = tid >> 6, lane = tid & 63;
    int l15 = lane & 15, lg = lane >> 4;
    int col = wv * 16 + l15;                // output column

    // stage Wh -> f16 linear (coalesced float4 reads)
    const float4* hwg = (const float4*)hw;
    #pragma unroll
    for (int q = 0; q < 8; q++) {
        float4 v = hwg[q * 512 + tid];
        union { _Float16 h[4]; double d64; } u;
        u.h[0] = (_Float16)v.x; u.h[1] = (_Float16)v.y;
        u.h[2] = (_Float16)v.z; u.h[3] = (_Float16)v.w;
        *(double*)&sb[(q * 512 + tid) * 4] = u.d64;
    }
    // zero h buffer 0 (incl. padding)
    for (int q = tid; q < 16 * 136 / 2; q += 512) ((unsigned*)&hbuf[0][0])[q] = 0u;
    __syncthreads();

    // one-time B-fragment gather: bf[ks][e] = Wh[ks*32 + lg*8 + e][col]
    f16x8 bf[4];
    #pragma unroll
    for (int ks = 0; ks < 4; ks++) {
        f16x8 t;
        #pragma unroll
        for (int e = 0; e < 8; e++) t[e] = sb[(ks * 32 + lg * 8 + e) * 128 + col];
        bf[ks] = t;
    }

    const float* XCp = wsf + XC_OFF + (size_t)(lg * 4) * 16384 + col;
    float4 xc0, xc1, xc2, xc3;
    LD_XC(xc0, 0) LD_XC(xc1, 1) LD_XC(xc2, 2) LD_XC(xc3, 3)
    float4 lastv = make_float4(0.f, 0.f, 0.f, 0.f);

    for (int i = 0; i < 128; i += 4) {
        QSTEP(xc0, 0, 0)
        QSTEP(xc1, 1, 1)
        QSTEP(xc2, 2, 0)
        QSTEP(xc3, 3, 1)
    }
    float* fp = out + (size_t)B_ * S_ * H_ + col;
    fp[(lg * 4 + 0) * 128] = lastv.x;
    fp[(lg * 4 + 1) * 128] = lastv.y;
    fp[(lg * 4 + 2) * 128] = lastv.z;
    fp[(lg * 4 + 3) * 128] = lastv.w;
}

extern "C" void kernel_launch(void* const* d_in, const int* in_sizes, int n_in,
                              void* d_out, int out_size, void* d_ws, size_t ws_size,
                              hipStream_t stream) {
    const float* x  = (const float*)d_in[0];
    const int*   tc = (const int*)d_in[1];
    const int*   dc = (const int*)d_in[2];
    const int*   mk = (const int*)d_in[3];   // bool masks pushed as int32
    const float* tw = (const float*)d_in[4];
    const float* dw = (const float*)d_in[5];
    const float* hw = (const float*)d_in[6];
    float*    out = (float*)d_out;
    float*    wsf = (float*)d_ws;
    unsigned* wsi = (unsigned*)d_ws;
    char*     wsb = (char*)d_ws;

    int useY = (ws_size >= NEED_BYTES) ? 1 : 0;
    if (!useY)  // fallback path accumulates into XC with atomics -> needs zeroed XC
        hipMemsetAsync(wsb, 0, (size_t)262144 * 4, stream);

    k_hist1<<<dim3(NB), dim3(256), 0, stream>>>(tc, dc, mk, wsi);
    k_scan_all<<<dim3(1), dim3(1024), 0, stream>>>(wsi);
    k_scatter<<<dim3(NB), dim3(256), 0, stream>>>(tc, dc, mk, wsi, useY);
    k_phaseA<<<dim3(NS, 16), dim3(256), 0, stream>>>(x, tw, wsi, wsf);
    k_phaseB<<<dim3(NS, 16), dim3(256), 0, stream>>>(dw, wsi, wsf, useY);
    if (useY) k_reduce<<<dim3(2048), dim3(128), 0, stream>>>(wsi, wsf);
    k_recur<<<dim3(1), dim3(512), 0, stream>>>(hw, wsf, out);
}

// Round 16
// 131.496 us; speedup vs baseline: 1.2382x; 1.2382x over previous
//
#include <hip/hip_runtime.h>
#include <math.h>

// STRNN: B=16, S=128, D=64, K=64, H=128, NSLOT+1=97 slots.
//
// Pipeline:
//  k_hist1    : per-block LDS histograms (64 blocks x 4096 elems = 32 rows/block)
//  k_scan_all : ONE combined exclusive scan over BH_T++BH_D + small (b,i) scan
//  k_scatter  : one pass; LDS cursors; emits t-sorted entries, d-sorted refs, Y slots
//  k_phaseA   : per t-bucket GEMM xt = x[b,j] @ Tw[t] (VALU f32) -> XT f16 [tpos][64]
//  k_phaseB   : per d-bucket GEMM y = xt @ Dw[d] via MFMA f16 -> Y f16 [dstpos][128]
//  k_reduce   : XC[b,i,:] = f32 sum of contiguous Y f16 rows (f16x8 vectorized)
//  k_recur    : (r9-proven) 2 waves/block, 1 col/lane, Wh in VGPRs as half2,
//               h in 512B LDS f16 dbuf, XC prefetched 4 deep, 1 barrier/step.
//
// ws requirement: ~54 MB for the atomic-free path (guarded; fallback = atomicAdd XC).

#define B_ 16
#define S_ 128
#define D_ 64
#define K_ 64
#define H_ 128
#define NS 97
#define NB 64        // histogram blocks; 4096 elems (32 rows) each: NB*32 == 2048 rows
#define MAXE 132096  // B * S*(S+1)/2  (upper bound on valid triples)

// u32-index offsets into ws
#define XC_OFF 0                   // f32 [2048][128]
#define BH_T   262144              // u32 [97][64]
#define BH_D   (BH_T + NS * NB)    // u32 [97][64]  (contiguous after BH_T!)
#define CNT_T  (BH_D + NS * NB)    // u32 [97]
#define CNT_D  (CNT_T + NS)        // u32 [97]
#define CNT_B  (CNT_D + NS)        // u32 [2048]
#define OFF_T  (CNT_B + 2048)      // u32 [98]
#define OFF_D  (OFF_T + 98)        // u32 [98]
#define OFF_B  (OFF_D + 98)        // u32 [2049]
#define ENT_T  291464              // u32 [MAXE]  (16B aligned; > all header offsets)
#define ENT_DX (ENT_T + MAXE)      // u32 [MAXE] xt-row index (t-sorted pos)
#define ENT_DP (ENT_DX + MAXE)     // u32 [MAXE] Y-row (dst-sorted pos) [or dst in fallback]
#define XT16_OFF (ENT_DP + MAXE)   // f16 [MAXE][64]  (MAXE*32 u32)
#define Y16_OFF  (XT16_OFF + MAXE * 32)  // f16 [MAXE][128] (MAXE*64 u32)
#define NEED_BYTES ((size_t)(Y16_OFF + (size_t)MAXE * 64) * 4)

typedef _Float16 h2_t __attribute__((ext_vector_type(2)));
typedef _Float16 f16x8 __attribute__((ext_vector_type(8)));
typedef float f32x4 __attribute__((ext_vector_type(4)));

#if __has_builtin(__builtin_amdgcn_fdot2)
#define FDOT2(a, b, c) __builtin_amdgcn_fdot2((a), (b), (c), false)
#else
#define FDOT2(a, b, c) ((c) + (float)(a)[0] * (float)(b)[0] + (float)(a)[1] * (float)(b)[1])
#endif

// ---- binning: 64 blocks x 4096 elements (32 (b,i) rows per block) ----

__global__ __launch_bounds__(256) void k_hist1(const int* __restrict__ tc,
                                               const int* __restrict__ dc,
                                               const int* __restrict__ mk,
                                               unsigned* wsi) {
    __shared__ unsigned ht[NS], hd[NS], hb[32];
    int tid = threadIdx.x, blk = blockIdx.x;
    if (tid < NS) { ht[tid] = 0; hd[tid] = 0; }
    if (tid < 32) hb[tid] = 0;
    __syncthreads();
    int base = blk * 4096;
    #pragma unroll
    for (int u = 0; u < 16; u++) {
        int idx = base + tid + u * 256;
        int i = (idx >> 7) & 127, j = idx & 127;
        if (j <= i && mk[idx] != 0) {
            atomicAdd(&ht[tc[idx]], 1u);
            atomicAdd(&hd[dc[idx]], 1u);
            atomicAdd(&hb[(idx >> 7) & 31], 1u);
        }
    }
    __syncthreads();
    if (tid < NS) {
        wsi[BH_T + tid * NB + blk] = ht[tid];
        wsi[BH_D + tid * NB + blk] = hd[tid];
    }
    if (tid < 32) wsi[CNT_B + blk * 32 + tid] = hb[tid];
}

template <int CH>
__device__ unsigned scan_region(unsigned* in, unsigned* out, int L, unsigned* s) {
    int tid = threadIdx.x;
    unsigned loc[CH], sum = 0;
    #pragma unroll
    for (int k = 0; k < CH; k++) {
        int idx = tid * CH + k;
        loc[k] = (idx < L) ? in[idx] : 0u;
        sum += loc[k];
    }
    s[tid] = sum;
    __syncthreads();
    for (int o = 1; o < 1024; o <<= 1) {
        unsigned a = (tid >= o) ? s[tid - o] : 0u;
        __syncthreads();
        s[tid] += a;
        __syncthreads();
    }
    unsigned total = s[1023];
    unsigned run = s[tid] - sum;
    __syncthreads();
    #pragma unroll
    for (int k = 0; k < CH; k++) {
        int idx = tid * CH + k;
        if (idx < L) { out[idx] = run; run += loc[k]; }
    }
    __syncthreads();
    return total;
}

__global__ __launch_bounds__(1024) void k_scan_all(unsigned* wsi) {
    __shared__ unsigned s[1024];
    int tid = threadIdx.x;

    // ONE combined scan over BH_T ++ BH_D (contiguous, 2*NS*NB = 12416 <= 1024*13)
    unsigned tot = scan_region<13>(wsi + BH_T, wsi + BH_T, 2 * NS * NB, s);
    unsigned totT = wsi[BH_D];          // exclusive prefix at start of D part == totT
    if (tid < NS) {
        unsigned b0 = wsi[BH_T + tid * NB];
        unsigned b1 = (tid < NS - 1) ? wsi[BH_T + (tid + 1) * NB] : totT;
        wsi[OFF_T + tid] = b0;
        wsi[CNT_T + tid] = b1 - b0;
        unsigned d0 = wsi[BH_D + tid * NB];
        unsigned d1 = (tid < NS - 1) ? wsi[BH_D + (tid + 1) * NB] : tot;
        wsi[OFF_D + tid] = d0 - totT;
        wsi[CNT_D + tid] = d1 - d0;
    }
    if (tid == 0) { wsi[OFF_T + NS] = totT; wsi[OFF_D + NS] = tot - totT; }
    __syncthreads();

    unsigned totB = scan_region<2>(wsi + CNT_B, wsi + OFF_B, 2048, s);
    if (tid == 0) wsi[OFF_B + 2048] = totB;
}

__global__ __launch_bounds__(256) void k_scatter(const int* __restrict__ tc,
                                                 const int* __restrict__ dc,
                                                 const int* __restrict__ mk,
                                                 unsigned* wsi, int useY) {
    __shared__ unsigned ct[NS], cd[NS], cb[32];
    int tid = threadIdx.x, blk = blockIdx.x;
    unsigned totT = wsi[OFF_T + NS];    // D-part bases are shifted by totT
    if (tid < NS) {
        ct[tid] = wsi[BH_T + tid * NB + blk];
        cd[tid] = wsi[BH_D + tid * NB + blk] - totT;
    }
    if (tid < 32) cb[tid] = wsi[OFF_B + blk * 32 + tid];
    __syncthreads();
    int base = blk * 4096;
    #pragma unroll
    for (int u = 0; u < 16; u++) {
        int idx = base + tid + u * 256;
        int i = (idx >> 7) & 127, j = idx & 127, b = idx >> 14;
        if (j <= i && mk[idx] != 0) {
            unsigned t = (unsigned)tc[idx], d = (unsigned)dc[idx];
            unsigned tpos = atomicAdd(&ct[t], 1u);
            wsi[ENT_T + tpos] = (unsigned)b | ((unsigned)i << 4) | ((unsigned)j << 11)
                              | (t << 18) | (d << 25);
            unsigned dpos = atomicAdd(&cd[d], 1u);
            unsigned yp = useY ? atomicAdd(&cb[(idx >> 7) & 31], 1u) : (unsigned)(idx >> 7);
            wsi[ENT_DX + dpos] = tpos;
            wsi[ENT_DP + dpos] = yp;
        }
    }
}

// phase A (VALU f32, r12-proven): xt[entry][kk] = sum_dd x[b,j][dd]*Tw[t][dd][kk];
// XT stored as f16.
__global__ __launch_bounds__(256) void k_phaseA(const float* __restrict__ x,
                                                const float* __restrict__ tw,
                                                unsigned* wsi, float* wsf) {
    int t = blockIdx.x, c = blockIdx.y;
    int rows = (int)wsi[CNT_T + t] - c * 128;
    if (rows <= 0) return;
    if (rows > 128) rows = 128;
    unsigned base = wsi[OFF_T + t] + c * 128;

    __shared__ float stw[4096];     // Tw[t] row-major [dd][kk]
    __shared__ float sx[8192];      // x rows, XOR-swizzled in 4-float units
    __shared__ unsigned ent[128];
    int tid = threadIdx.x;

    const float4* twg = (const float4*)(tw + t * 4096);
    float4* stw4 = (float4*)stw;
    #pragma unroll
    for (int q = 0; q < 4; q++) stw4[q * 256 + tid] = twg[q * 256 + tid];
    if (tid < 128) ent[tid] = (tid < rows) ? wsi[ENT_T + base + tid] : 0u;
    __syncthreads();

    int lane16 = tid & 15, rquot = tid >> 4;
    #pragma unroll
    for (int p = 0; p < 8; p++) {
        int r = p * 16 + rquot;
        float4 v = make_float4(0.f, 0.f, 0.f, 0.f);
        if (r < rows) {
            unsigned e = ent[r];
            int b = e & 15, j = (e >> 11) & 127;
            v = *(const float4*)(x + (b * S_ + j) * D_ + lane16 * 4);
        }
        int col4 = lane16 ^ (r & 15);
        float* dst = &sx[r * 64 + col4 * 4];
        dst[0] = v.x; dst[1] = v.y; dst[2] = v.z; dst[3] = v.w;
    }
    __syncthreads();

    int rgrp = tid & 15, cgrp = tid >> 4;   // 8 rows (rgrp+16i) x 4 cols (cgrp*4..)
    float4 acc[8];
    #pragma unroll
    for (int i = 0; i < 8; i++) acc[i] = make_float4(0.f, 0.f, 0.f, 0.f);
    #pragma unroll 4
    for (int dd = 0; dd < 64; dd++) {
        float4 w = stw4[dd * 16 + cgrp];
        int s_idx = (((dd >> 2) ^ rgrp) << 2) + (dd & 3);
        #pragma unroll
        for (int i = 0; i < 8; i++) {
            float a = sx[(rgrp + 16 * i) * 64 + s_idx];
            acc[i].x += a * w.x; acc[i].y += a * w.y;
            acc[i].z += a * w.z; acc[i].w += a * w.w;
        }
    }
    _Float16* XT = (_Float16*)(wsf + XT16_OFF);
    #pragma unroll
    for (int i = 0; i < 8; i++) {
        int r = rgrp + 16 * i;
        if (r < rows) {
            union { _Float16 h[4]; double d64; } u;
            u.h[0] = (_Float16)acc[i].x; u.h[1] = (_Float16)acc[i].y;
            u.h[2] = (_Float16)acc[i].z; u.h[3] = (_Float16)acc[i].w;
            *(double*)&XT[(size_t)(base + r) * 64 + cgrp * 4] = u.d64;
        }
    }
}

// phase B (MFMA f16): y[rows x 128] = XT16-rows[rows x 64] @ Dw[d][64 x 128] -> Y f16.
__global__ __launch_bounds__(256) void k_phaseB(const float* __restrict__ dw,
                                                unsigned* wsi, float* wsf, int useY) {
    int d = blockIdx.x, c = blockIdx.y;
    int rows = (int)wsi[CNT_D + d] - c * 128;
    if (rows <= 0) return;
    if (rows > 128) rows = 128;
    unsigned base = wsi[OFF_D + d] + c * 128;

    __shared__ _Float16 sa[128 * 64];     // A: XT rows f16, chunk-swizzled (16 KB)
    __shared__ _Float16 sb[64 * 128];     // B: Dw f16 [k][h] linear (16 KB)
    __shared__ unsigned entx_s[128], entp_s[128];
    int tid = threadIdx.x;

    if (tid < 128) {
        entx_s[tid] = (tid < rows) ? wsi[ENT_DX + base + tid] : 0u;
        entp_s[tid] = (tid < rows) ? wsi[ENT_DP + base + tid] : 0u;
    }
    const float4* dwg = (const float4*)(dw + (size_t)d * 8192);
    #pragma unroll
    for (int q = 0; q < 8; q++) {
        float4 v = dwg[q * 256 + tid];
        union { _Float16 h[4]; double d64; } u;
        u.h[0] = (_Float16)v.x; u.h[1] = (_Float16)v.y;
        u.h[2] = (_Float16)v.z; u.h[3] = (_Float16)v.w;
        *(double*)&sb[(q * 256 + tid) * 4] = u.d64;
    }
    __syncthreads();

    {
        int r = tid >> 1, hh = tid & 1;
        const _Float16* XT = (const _Float16*)(wsf + XT16_OFF);
        const f16x8* src = (const f16x8*)(XT + (size_t)entx_s[r] * 64 + hh * 32);
        #pragma unroll
        for (int mm = 0; mm < 4; mm++) {
            f16x8 hv = {0, 0, 0, 0, 0, 0, 0, 0};
            if (r < rows) hv = src[mm];
            int chunk = hh * 4 + mm;
            *(f16x8*)&sa[r * 64 + (chunk ^ (r & 7)) * 8] = hv;
        }
    }
    __syncthreads();

    int w = tid >> 6, lane = tid & 63;
    int l15 = lane & 15, lg = lane >> 4;
    f16x8 bf[2][2];
    #pragma unroll
    for (int n = 0; n < 2; n++) {
        int col = w * 32 + n * 16 + l15;
        #pragma unroll
        for (int ks = 0; ks < 2; ks++) {
            int kb = ks * 32 + lg * 8;
            f16x8 t;
            #pragma unroll
            for (int e = 0; e < 8; e++) t[e] = sb[(kb + e) * 128 + col];
            bf[n][ks] = t;
        }
    }
    f32x4 acc[8][2];
    f32x4 z = {0.f, 0.f, 0.f, 0.f};
    #pragma unroll
    for (int m = 0; m < 8; m++) { acc[m][0] = z; acc[m][1] = z; }

    #pragma unroll
    for (int m = 0; m < 8; m++) {
        int row = m * 16 + l15;
        f16x8 a0 = *(f16x8*)&sa[row * 64 + ((lg) ^ (row & 7)) * 8];
        f16x8 a1 = *(f16x8*)&sa[row * 64 + ((4 + lg) ^ (row & 7)) * 8];
        #pragma unroll
        for (int n = 0; n < 2; n++) {
            acc[m][n] = __builtin_amdgcn_mfma_f32_16x16x32_f16(a0, bf[n][0], acc[m][n], 0, 0, 0);
            acc[m][n] = __builtin_amdgcn_mfma_f32_16x16x32_f16(a1, bf[n][1], acc[m][n], 0, 0, 0);
        }
    }

    if (useY) {
        _Float16* Y16 = (_Float16*)(wsf + Y16_OFF);
        #pragma unroll
        for (int m = 0; m < 8; m++) {
            #pragma unroll
            for (int reg = 0; reg < 4; reg++) {
                int row = m * 16 + lg * 4 + reg;
                if (row < rows) {
                    _Float16* p = Y16 + (size_t)entp_s[row] * 128 + w * 32 + l15;
                    p[0]  = (_Float16)acc[m][0][reg];
                    p[16] = (_Float16)acc[m][1][reg];
                }
            }
        }
    } else {
        float* XC = wsf + XC_OFF;
        #pragma unroll
        for (int m = 0; m < 8; m++) {
            #pragma unroll
            for (int reg = 0; reg < 4; reg++) {
                int row = m * 16 + lg * 4 + reg;
                if (row < rows) {
                    float* p = XC + (size_t)entp_s[row] * 128 + w * 32 + l15;
                    atomicAdd(p + 0,  acc[m][0][reg]);
                    atomicAdd(p + 16, acc[m][1][reg]);
                }
            }
        }
    }
}

// XC[b,i,:] = f32 sum of contiguous Y16 rows; vectorized f16x8 loads.
// Thread = (row-slot rq = tid>>4, col-slot cs = tid&15, 8 cols each).
__global__ __launch_bounds__(128) void k_reduce(unsigned* wsi, float* wsf) {
    __shared__ float part[8][128];
    int bi = blockIdx.x, tid = threadIdx.x;
    unsigned n = wsi[CNT_B + bi], off = wsi[OFF_B + bi];
    int rq = tid >> 4, cs = tid & 15;
    const _Float16* Yb = (const _Float16*)(wsf + Y16_OFF) + (size_t)off * 128 + cs * 8;
    float a0 = 0.f, a1 = 0.f, a2 = 0.f, a3 = 0.f;
    float a4 = 0.f, a5 = 0.f, a6 = 0.f, a7 = 0.f;
    for (unsigned e = rq; e < n; e += 8) {
        f16x8 v = *(const f16x8*)&Yb[(size_t)e * 128];
        a0 += (float)v[0]; a1 += (float)v[1]; a2 += (float)v[2]; a3 += (float)v[3];
        a4 += (float)v[4]; a5 += (float)v[5]; a6 += (float)v[6]; a7 += (float)v[7];
    }
    float* pp = &part[rq][cs * 8];
    pp[0] = a0; pp[1] = a1; pp[2] = a2; pp[3] = a3;
    pp[4] = a4; pp[5] = a5; pp[6] = a6; pp[7] = a7;
    __syncthreads();
    // column tid: sum the 8 row-slot partials
    float s = (part[0][tid] + part[1][tid]) + (part[2][tid] + part[3][tid])
            + (part[4][tid] + part[5][tid]) + (part[6][tid] + part[7][tid]);
    wsf[XC_OFF + (size_t)bi * 128 + tid] = s;
}

// recurrence (r9 best): one block (128 thr = 2 waves) per b; lane owns col =
// wv*64+lane; Wh column in 64 half2 VGPRs; h in 512B LDS f16 dbuf; XC prefetched
// FOUR steps ahead into named registers; one barrier per step.
#define RSTEP(XCREG, IDX, CURB)                                                \
    {                                                                          \
        float xc_use = XCREG;                                                  \
        if (i + 4 + (IDX) < 128) XCREG = XC[(i + 4 + (IDX)) * 128];            \
        const float4* hb = (const float4*)&h16[CURB][0];                       \
        float a0 = 0.f, a1 = 0.f, a2 = 0.f, a3 = 0.f;                          \
        _Pragma("unroll")                                                      \
        for (int q = 0; q < 16; q++) {                                         \
            union { float4 f4; h2_t h2[4]; } u;                                \
            u.f4 = hb[q];                                                      \
            a0 = FDOT2(u.h2[0], w2[4 * q + 0], a0);                            \
            a1 = FDOT2(u.h2[1], w2[4 * q + 1], a1);                            \
            a2 = FDOT2(u.h2[2], w2[4 * q + 2], a2);                            \
            a3 = FDOT2(u.h2[3], w2[4 * q + 3], a3);                            \
        }                                                                      \
        float v = xc_use + (a0 + a1) + (a2 + a3);                              \
        v = 1.f / (1.f + __expf(-v));                                          \
        val = v;                                                               \
        ((_Float16*)&h16[(CURB) ^ 1][0])[col] = (_Float16)v;                   \
        out[(size_t)(b * 128 + i + (IDX)) * 128 + col] = v;                    \
        __syncthreads();                                                       \
    }

__global__ __launch_bounds__(128) void k_recur(const float* __restrict__ hw,
                                               const float* __restrict__ wsf,
                                               float* __restrict__ out) {
    int b = blockIdx.x;
    __shared__ h2_t h16[2][64];         // [buf][64 half2] = 128 halves
    int tid = threadIdx.x;
    int lane = tid & 63, wv = tid >> 6;
    int col = wv * 64 + lane;

    h2_t w2[64];
    #pragma unroll
    for (int m = 0; m < 64; m++) {
        h2_t p;
        p[0] = (_Float16)hw[(2 * m) * 128 + col];       // coalesced across lanes
        p[1] = (_Float16)hw[(2 * m + 1) * 128 + col];
        w2[m] = p;
    }
    if (tid < 64) h16[0][tid] = (h2_t)(_Float16)0.f;
    __syncthreads();

    const float* XC = wsf + XC_OFF + (size_t)b * 128 * 128 + col;
    float xc0 = XC[0 * 128], xc1 = XC[1 * 128], xc2 = XC[2 * 128], xc3 = XC[3 * 128];
    float val = 0.f;
    for (int i = 0; i < 128; i += 4) {
        RSTEP(xc0, 0, 0)
        RSTEP(xc1, 1, 1)
        RSTEP(xc2, 2, 0)
        RSTEP(xc3, 3, 1)
    }
    out[(size_t)B_ * S_ * H_ + b * 128 + col] = val;
}

extern "C" void kernel_launch(void* const* d_in, const int* in_sizes, int n_in,
                              void* d_out, int out_size, void* d_ws, size_t ws_size,
                              hipStream_t stream) {
    const float* x  = (const float*)d_in[0];
    const int*   tc = (const int*)d_in[1];
    const int*   dc = (const int*)d_in[2];
    const int*   mk = (const int*)d_in[3];   // bool masks pushed as int32
    const float* tw = (const float*)d_in[4];
    const float* dw = (const float*)d_in[5];
    const float* hw = (const float*)d_in[6];
    float*    out = (float*)d_out;
    float*    wsf = (float*)d_ws;
    unsigned* wsi = (unsigned*)d_ws;
    char*     wsb = (char*)d_ws;

    int useY = (ws_size >= NEED_BYTES) ? 1 : 0;
    if (!useY)  // fallback path accumulates into XC with atomics -> needs zeroed XC
        hipMemsetAsync(wsb, 0, (size_t)262144 * 4, stream);

    k_hist1<<<dim3(NB), dim3(256), 0, stream>>>(tc, dc, mk, wsi);
    k_scan_all<<<dim3(1), dim3(1024), 0, stream>>>(wsi);
    k_scatter<<<dim3(NB), dim3(256), 0, stream>>>(tc, dc, mk, wsi, useY);
    k_phaseA<<<dim3(NS, 16), dim3(256), 0, stream>>>(x, tw, wsi, wsf);
    k_phaseB<<<dim3(NS, 16), dim3(256), 0, stream>>>(dw, wsi, wsf, useY);
    if (useY) k_reduce<<<dim3(2048), dim3(128), 0, stream>>>(wsi, wsf);
    k_recur<<<dim3(16), dim3(128), 0, stream>>>(hw, wsf, out);
}

// Round 17
// 125.660 us; speedup vs baseline: 1.2957x; 1.0464x over previous
//
#include <hip/hip_runtime.h>
#include <math.h>

// STRNN: B=16, S=128, D=64, K=64, H=128, NSLOT+1=97 slots.
//
// Pipeline:
//  k_hist1    : per-block LDS histograms (64 blocks x 4096 elems = 32 rows/block)
//  k_scan_all : ONE combined exclusive scan over BH_T++BH_D + small (b,i) scan
//  k_scatter  : one pass; LDS cursors; emits t-sorted entries, d-sorted refs, Y slots
//  k_phaseA   : per t-bucket GEMM xt = x[b,j] @ Tw[t] (VALU f32) -> XT f16 [tpos][64]
//  k_phaseB   : per d-bucket GEMM y = xt @ Dw[d] via MFMA f16 -> Y f16 [dstpos][128]
//  k_reduce   : XC[b,i,:] = f32 sum of contiguous Y f16 rows (f16x8 vectorized)
//  k_recur    : 4 waves/block, IN-WAVE K-split: thread=(col, khalf), 32 dot2/lane,
//               halves combined via __shfl_xor(p,32) (same wave!), ONE barrier/step,
//               Wh half-col in 32 half2 VGPRs, h in 512B LDS f16 dbuf, XC 4-deep.
//
// ws requirement: ~54 MB for the atomic-free path (guarded; fallback = atomicAdd XC).

#define B_ 16
#define S_ 128
#define D_ 64
#define K_ 64
#define H_ 128
#define NS 97
#define NB 64        // histogram blocks; 4096 elems (32 rows) each: NB*32 == 2048 rows
#define MAXE 132096  // B * S*(S+1)/2  (upper bound on valid triples)

// u32-index offsets into ws
#define XC_OFF 0                   // f32 [2048][128]
#define BH_T   262144              // u32 [97][64]
#define BH_D   (BH_T + NS * NB)    // u32 [97][64]  (contiguous after BH_T!)
#define CNT_T  (BH_D + NS * NB)    // u32 [97]
#define CNT_D  (CNT_T + NS)        // u32 [97]
#define CNT_B  (CNT_D + NS)        // u32 [2048]
#define OFF_T  (CNT_B + 2048)      // u32 [98]
#define OFF_D  (OFF_T + 98)        // u32 [98]
#define OFF_B  (OFF_D + 98)        // u32 [2049]
#define ENT_T  291464              // u32 [MAXE]  (16B aligned; > all header offsets)
#define ENT_DX (ENT_T + MAXE)      // u32 [MAXE] xt-row index (t-sorted pos)
#define ENT_DP (ENT_DX + MAXE)     // u32 [MAXE] Y-row (dst-sorted pos) [or dst in fallback]
#define XT16_OFF (ENT_DP + MAXE)   // f16 [MAXE][64]  (MAXE*32 u32)
#define Y16_OFF  (XT16_OFF + MAXE * 32)  // f16 [MAXE][128] (MAXE*64 u32)
#define NEED_BYTES ((size_t)(Y16_OFF + (size_t)MAXE * 64) * 4)

typedef _Float16 h2_t __attribute__((ext_vector_type(2)));
typedef _Float16 f16x8 __attribute__((ext_vector_type(8)));
typedef float f32x4 __attribute__((ext_vector_type(4)));

#if __has_builtin(__builtin_amdgcn_fdot2)
#define FDOT2(a, b, c) __builtin_amdgcn_fdot2((a), (b), (c), false)
#else
#define FDOT2(a, b, c) ((c) + (float)(a)[0] * (float)(b)[0] + (float)(a)[1] * (float)(b)[1])
#endif

// ---- binning: 64 blocks x 4096 elements (32 (b,i) rows per block) ----

__global__ __launch_bounds__(256) void k_hist1(const int* __restrict__ tc,
                                               const int* __restrict__ dc,
                                               const int* __restrict__ mk,
                                               unsigned* wsi) {
    __shared__ unsigned ht[NS], hd[NS], hb[32];
    int tid = threadIdx.x, blk = blockIdx.x;
    if (tid < NS) { ht[tid] = 0; hd[tid] = 0; }
    if (tid < 32) hb[tid] = 0;
    __syncthreads();
    int base = blk * 4096;
    #pragma unroll
    for (int u = 0; u < 16; u++) {
        int idx = base + tid + u * 256;
        int i = (idx >> 7) & 127, j = idx & 127;
        if (j <= i && mk[idx] != 0) {
            atomicAdd(&ht[tc[idx]], 1u);
            atomicAdd(&hd[dc[idx]], 1u);
            atomicAdd(&hb[(idx >> 7) & 31], 1u);
        }
    }
    __syncthreads();
    if (tid < NS) {
        wsi[BH_T + tid * NB + blk] = ht[tid];
        wsi[BH_D + tid * NB + blk] = hd[tid];
    }
    if (tid < 32) wsi[CNT_B + blk * 32 + tid] = hb[tid];
}

template <int CH>
__device__ unsigned scan_region(unsigned* in, unsigned* out, int L, unsigned* s) {
    int tid = threadIdx.x;
    unsigned loc[CH], sum = 0;
    #pragma unroll
    for (int k = 0; k < CH; k++) {
        int idx = tid * CH + k;
        loc[k] = (idx < L) ? in[idx] : 0u;
        sum += loc[k];
    }
    s[tid] = sum;
    __syncthreads();
    for (int o = 1; o < 1024; o <<= 1) {
        unsigned a = (tid >= o) ? s[tid - o] : 0u;
        __syncthreads();
        s[tid] += a;
        __syncthreads();
    }
    unsigned total = s[1023];
    unsigned run = s[tid] - sum;
    __syncthreads();
    #pragma unroll
    for (int k = 0; k < CH; k++) {
        int idx = tid * CH + k;
        if (idx < L) { out[idx] = run; run += loc[k]; }
    }
    __syncthreads();
    return total;
}

__global__ __launch_bounds__(1024) void k_scan_all(unsigned* wsi) {
    __shared__ unsigned s[1024];
    int tid = threadIdx.x;

    // ONE combined scan over BH_T ++ BH_D (contiguous, 2*NS*NB = 12416 <= 1024*13)
    unsigned tot = scan_region<13>(wsi + BH_T, wsi + BH_T, 2 * NS * NB, s);
    unsigned totT = wsi[BH_D];          // exclusive prefix at start of D part == totT
    if (tid < NS) {
        unsigned b0 = wsi[BH_T + tid * NB];
        unsigned b1 = (tid < NS - 1) ? wsi[BH_T + (tid + 1) * NB] : totT;
        wsi[OFF_T + tid] = b0;
        wsi[CNT_T + tid] = b1 - b0;
        unsigned d0 = wsi[BH_D + tid * NB];
        unsigned d1 = (tid < NS - 1) ? wsi[BH_D + (tid + 1) * NB] : tot;
        wsi[OFF_D + tid] = d0 - totT;
        wsi[CNT_D + tid] = d1 - d0;
    }
    if (tid == 0) { wsi[OFF_T + NS] = totT; wsi[OFF_D + NS] = tot - totT; }
    __syncthreads();

    unsigned totB = scan_region<2>(wsi + CNT_B, wsi + OFF_B, 2048, s);
    if (tid == 0) wsi[OFF_B + 2048] = totB;
}

__global__ __launch_bounds__(256) void k_scatter(const int* __restrict__ tc,
                                                 const int* __restrict__ dc,
                                                 const int* __restrict__ mk,
                                                 unsigned* wsi, int useY) {
    __shared__ unsigned ct[NS], cd[NS], cb[32];
    int tid = threadIdx.x, blk = blockIdx.x;
    unsigned totT = wsi[OFF_T + NS];    // D-part bases are shifted by totT
    if (tid < NS) {
        ct[tid] = wsi[BH_T + tid * NB + blk];
        cd[tid] = wsi[BH_D + tid * NB + blk] - totT;
    }
    if (tid < 32) cb[tid] = wsi[OFF_B + blk * 32 + tid];
    __syncthreads();
    int base = blk * 4096;
    #pragma unroll
    for (int u = 0; u < 16; u++) {
        int idx = base + tid + u * 256;
        int i = (idx >> 7) & 127, j = idx & 127, b = idx >> 14;
        if (j <= i && mk[idx] != 0) {
            unsigned t = (unsigned)tc[idx], d = (unsigned)dc[idx];
            unsigned tpos = atomicAdd(&ct[t], 1u);
            wsi[ENT_T + tpos] = (unsigned)b | ((unsigned)i << 4) | ((unsigned)j << 11)
                              | (t << 18) | (d << 25);
            unsigned dpos = atomicAdd(&cd[d], 1u);
            unsigned yp = useY ? atomicAdd(&cb[(idx >> 7) & 31], 1u) : (unsigned)(idx >> 7);
            wsi[ENT_DX + dpos] = tpos;
            wsi[ENT_DP + dpos] = yp;
        }
    }
}

// phase A (VALU f32, r12-proven): xt[entry][kk] = sum_dd x[b,j][dd]*Tw[t][dd][kk];
// XT stored as f16.
__global__ __launch_bounds__(256) void k_phaseA(const float* __restrict__ x,
                                                const float* __restrict__ tw,
                                                unsigned* wsi, float* wsf) {
    int t = blockIdx.x, c = blockIdx.y;
    int rows = (int)wsi[CNT_T + t] - c * 128;
    if (rows <= 0) return;
    if (rows > 128) rows = 128;
    unsigned base = wsi[OFF_T + t] + c * 128;

    __shared__ float stw[4096];     // Tw[t] row-major [dd][kk]
    __shared__ float sx[8192];      // x rows, XOR-swizzled in 4-float units
    __shared__ unsigned ent[128];
    int tid = threadIdx.x;

    const float4* twg = (const float4*)(tw + t * 4096);
    float4* stw4 = (float4*)stw;
    #pragma unroll
    for (int q = 0; q < 4; q++) stw4[q * 256 + tid] = twg[q * 256 + tid];
    if (tid < 128) ent[tid] = (tid < rows) ? wsi[ENT_T + base + tid] : 0u;
    __syncthreads();

    int lane16 = tid & 15, rquot = tid >> 4;
    #pragma unroll
    for (int p = 0; p < 8; p++) {
        int r = p * 16 + rquot;
        float4 v = make_float4(0.f, 0.f, 0.f, 0.f);
        if (r < rows) {
            unsigned e = ent[r];
            int b = e & 15, j = (e >> 11) & 127;
            v = *(const float4*)(x + (b * S_ + j) * D_ + lane16 * 4);
        }
        int col4 = lane16 ^ (r & 15);
        float* dst = &sx[r * 64 + col4 * 4];
        dst[0] = v.x; dst[1] = v.y; dst[2] = v.z; dst[3] = v.w;
    }
    __syncthreads();

    int rgrp = tid & 15, cgrp = tid >> 4;   // 8 rows (rgrp+16i) x 4 cols (cgrp*4..)
    float4 acc[8];
    #pragma unroll
    for (int i = 0; i < 8; i++) acc[i] = make_float4(0.f, 0.f, 0.f, 0.f);
    #pragma unroll 4
    for (int dd = 0; dd < 64; dd++) {
        float4 w = stw4[dd * 16 + cgrp];
        int s_idx = (((dd >> 2) ^ rgrp) << 2) + (dd & 3);
        #pragma unroll
        for (int i = 0; i < 8; i++) {
            float a = sx[(rgrp + 16 * i) * 64 + s_idx];
            acc[i].x += a * w.x; acc[i].y += a * w.y;
            acc[i].z += a * w.z; acc[i].w += a * w.w;
        }
    }
    _Float16* XT = (_Float16*)(wsf + XT16_OFF);
    #pragma unroll
    for (int i = 0; i < 8; i++) {
        int r = rgrp + 16 * i;
        if (r < rows) {
            union { _Float16 h[4]; double d64; } u;
            u.h[0] = (_Float16)acc[i].x; u.h[1] = (_Float16)acc[i].y;
            u.h[2] = (_Float16)acc[i].z; u.h[3] = (_Float16)acc[i].w;
            *(double*)&XT[(size_t)(base + r) * 64 + cgrp * 4] = u.d64;
        }
    }
}

// phase B (MFMA f16): y[rows x 128] = XT16-rows[rows x 64] @ Dw[d][64 x 128] -> Y f16.
__global__ __launch_bounds__(256) void k_phaseB(const float* __restrict__ dw,
                                                unsigned* wsi, float* wsf, int useY) {
    int d = blockIdx.x, c = blockIdx.y;
    int rows = (int)wsi[CNT_D + d] - c * 128;
    if (rows <= 0) return;
    if (rows > 128) rows = 128;
    unsigned base = wsi[OFF_D + d] + c * 128;

    __shared__ _Float16 sa[128 * 64];     // A: XT rows f16, chunk-swizzled (16 KB)
    __shared__ _Float16 sb[64 * 128];     // B: Dw f16 [k][h] linear (16 KB)
    __shared__ unsigned entx_s[128], entp_s[128];
    int tid = threadIdx.x;

    if (tid < 128) {
        entx_s[tid] = (tid < rows) ? wsi[ENT_DX + base + tid] : 0u;
        entp_s[tid] = (tid < rows) ? wsi[ENT_DP + base + tid] : 0u;
    }
    const float4* dwg = (const float4*)(dw + (size_t)d * 8192);
    #pragma unroll
    for (int q = 0; q < 8; q++) {
        float4 v = dwg[q * 256 + tid];
        union { _Float16 h[4]; double d64; } u;
        u.h[0] = (_Float16)v.x; u.h[1] = (_Float16)v.y;
        u.h[2] = (_Float16)v.z; u.h[3] = (_Float16)v.w;
        *(double*)&sb[(q * 256 + tid) * 4] = u.d64;
    }
    __syncthreads();

    {
        int r = tid >> 1, hh = tid & 1;
        const _Float16* XT = (const _Float16*)(wsf + XT16_OFF);
        const f16x8* src = (const f16x8*)(XT + (size_t)entx_s[r] * 64 + hh * 32);
        #pragma unroll
        for (int mm = 0; mm < 4; mm++) {
            f16x8 hv = {0, 0, 0, 0, 0, 0, 0, 0};
            if (r < rows) hv = src[mm];
            int chunk = hh * 4 + mm;
            *(f16x8*)&sa[r * 64 + (chunk ^ (r & 7)) * 8] = hv;
        }
    }
    __syncthreads();

    int w = tid >> 6, lane = tid & 63;
    int l15 = lane & 15, lg = lane >> 4;
    f16x8 bf[2][2];
    #pragma unroll
    for (int n = 0; n < 2; n++) {
        int col = w * 32 + n * 16 + l15;
        #pragma unroll
        for (int ks = 0; ks < 2; ks++) {
            int kb = ks * 32 + lg * 8;
            f16x8 t;
            #pragma unroll
            for (int e = 0; e < 8; e++) t[e] = sb[(kb + e) * 128 + col];
            bf[n][ks] = t;
        }
    }
    f32x4 acc[8][2];
    f32x4 z = {0.f, 0.f, 0.f, 0.f};
    #pragma unroll
    for (int m = 0; m < 8; m++) { acc[m][0] = z; acc[m][1] = z; }

    #pragma unroll
    for (int m = 0; m < 8; m++) {
        int row = m * 16 + l15;
        f16x8 a0 = *(f16x8*)&sa[row * 64 + ((lg) ^ (row & 7)) * 8];
        f16x8 a1 = *(f16x8*)&sa[row * 64 + ((4 + lg) ^ (row & 7)) * 8];
        #pragma unroll
        for (int n = 0; n < 2; n++) {
            acc[m][n] = __builtin_amdgcn_mfma_f32_16x16x32_f16(a0, bf[n][0], acc[m][n], 0, 0, 0);
            acc[m][n] = __builtin_amdgcn_mfma_f32_16x16x32_f16(a1, bf[n][1], acc[m][n], 0, 0, 0);
        }
    }

    if (useY) {
        _Float16* Y16 = (_Float16*)(wsf + Y16_OFF);
        #pragma unroll
        for (int m = 0; m < 8; m++) {
            #pragma unroll
            for (int reg = 0; reg < 4; reg++) {
                int row = m * 16 + lg * 4 + reg;
                if (row < rows) {
                    _Float16* p = Y16 + (size_t)entp_s[row] * 128 + w * 32 + l15;
                    p[0]  = (_Float16)acc[m][0][reg];
                    p[16] = (_Float16)acc[m][1][reg];
                }
            }
        }
    } else {
        float* XC = wsf + XC_OFF;
        #pragma unroll
        for (int m = 0; m < 8; m++) {
            #pragma unroll
            for (int reg = 0; reg < 4; reg++) {
                int row = m * 16 + lg * 4 + reg;
                if (row < rows) {
                    float* p = XC + (size_t)entp_s[row] * 128 + w * 32 + l15;
                    atomicAdd(p + 0,  acc[m][0][reg]);
                    atomicAdd(p + 16, acc[m][1][reg]);
                }
            }
        }
    }
}

// XC[b,i,:] = f32 sum of contiguous Y16 rows; vectorized f16x8 loads.
__global__ __launch_bounds__(128) void k_reduce(unsigned* wsi, float* wsf) {
    __shared__ float part[8][128];
    int bi = blockIdx.x, tid = threadIdx.x;
    unsigned n = wsi[CNT_B + bi], off = wsi[OFF_B + bi];
    int rq = tid >> 4, cs = tid & 15;
    const _Float16* Yb = (const _Float16*)(wsf + Y16_OFF) + (size_t)off * 128 + cs * 8;
    float a0 = 0.f, a1 = 0.f, a2 = 0.f, a3 = 0.f;
    float a4 = 0.f, a5 = 0.f, a6 = 0.f, a7 = 0.f;
    for (unsigned e = rq; e < n; e += 8) {
        f16x8 v = *(const f16x8*)&Yb[(size_t)e * 128];
        a0 += (float)v[0]; a1 += (float)v[1]; a2 += (float)v[2]; a3 += (float)v[3];
        a4 += (float)v[4]; a5 += (float)v[5]; a6 += (float)v[6]; a7 += (float)v[7];
    }
    float* pp = &part[rq][cs * 8];
    pp[0] = a0; pp[1] = a1; pp[2] = a2; pp[3] = a3;
    pp[4] = a4; pp[5] = a5; pp[6] = a6; pp[7] = a7;
    __syncthreads();
    float s = (part[0][tid] + part[1][tid]) + (part[2][tid] + part[3][tid])
            + (part[4][tid] + part[5][tid]) + (part[6][tid] + part[7][tid]);
    wsf[XC_OFF + (size_t)bi * 128 + tid] = s;
}

// recurrence: one block (256 thr = 4 waves) per batch b. IN-WAVE K-split:
// thread = (col = wv*32 + (lane&31), kh = lane>>5); lane holds w2[32] half2 =
// Wh[kh*64 .. +64)[col]. Per step: 8 bcast ds_read_b128 of own h-half, 32 dot2,
// __shfl_xor(p,32) combines K-halves IN-WAVE (vs r5's LDS+2-barrier: 1 barrier).
// kh==0 lanes do sigmoid + h16/out writes. XC prefetched 4 steps deep.
#define RSTEP(XCREG, IDX, CURB)                                                \
    {                                                                          \
        float xc_use = XCREG;                                                  \
        if (kh == 0 && i + 4 + (IDX) < 128) XCREG = XC[(i + 4 + (IDX)) * 128]; \
        const float4* hb = (const float4*)&h16[CURB][kh * 32];                 \
        float a0 = 0.f, a1 = 0.f, a2 = 0.f, a3 = 0.f;                          \
        _Pragma("unroll")                                                      \
        for (int q = 0; q < 8; q++) {                                          \
            union { float4 f4; h2_t h2[4]; } u;                                \
            u.f4 = hb[q];                                                      \
            a0 = FDOT2(u.h2[0], w2[4 * q + 0], a0);                            \
            a1 = FDOT2(u.h2[1], w2[4 * q + 1], a1);                            \
            a2 = FDOT2(u.h2[2], w2[4 * q + 2], a2);                            \
            a3 = FDOT2(u.h2[3], w2[4 * q + 3], a3);                            \
        }                                                                      \
        float p = (a0 + a1) + (a2 + a3);                                       \
        p += __shfl_xor(p, 32);                                                \
        if (kh == 0) {                                                         \
            float v = xc_use + p;                                              \
            v = 1.f / (1.f + __expf(-v));                                      \
            val = v;                                                           \
            ((_Float16*)&h16[(CURB) ^ 1][0])[col] = (_Float16)v;               \
            out[(size_t)(b * 128 + i + (IDX)) * 128 + col] = v;                \
        }                                                                      \
        __syncthreads();                                                       \
    }

__global__ __launch_bounds__(256) void k_recur(const float* __restrict__ hw,
                                               const float* __restrict__ wsf,
                                               float* __restrict__ out) {
    int b = blockIdx.x;
    __shared__ h2_t h16[2][64];         // [buf][64 half2] = 128 halves
    int tid = threadIdx.x;
    int lane = tid & 63, wv = tid >> 6;
    int c32 = lane & 31, kh = lane >> 5;
    int col = wv * 32 + c32;
    int k0 = kh * 64;

    h2_t w2[32];
    #pragma unroll
    for (int m = 0; m < 32; m++) {
        h2_t p;
        p[0] = (_Float16)hw[(k0 + 2 * m) * 128 + col];
        p[1] = (_Float16)hw[(k0 + 2 * m + 1) * 128 + col];
        w2[m] = p;
    }
    if (tid < 64) h16[0][tid] = (h2_t)(_Float16)0.f;
    __syncthreads();

    const float* XC = wsf + XC_OFF + (size_t)b * 128 * 128 + col;
    float xc0 = 0.f, xc1 = 0.f, xc2 = 0.f, xc3 = 0.f;
    if (kh == 0) {
        xc0 = XC[0 * 128]; xc1 = XC[1 * 128];
        xc2 = XC[2 * 128]; xc3 = XC[3 * 128];
    }
    float val = 0.f;
    for (int i = 0; i < 128; i += 4) {
        RSTEP(xc0, 0, 0)
        RSTEP(xc1, 1, 1)
        RSTEP(xc2, 2, 0)
        RSTEP(xc3, 3, 1)
    }
    if (kh == 0) out[(size_t)B_ * S_ * H_ + b * 128 + col] = val;
}

extern "C" void kernel_launch(void* const* d_in, const int* in_sizes, int n_in,
                              void* d_out, int out_size, void* d_ws, size_t ws_size,
                              hipStream_t stream) {
    const float* x  = (const float*)d_in[0];
    const int*   tc = (const int*)d_in[1];
    const int*   dc = (const int*)d_in[2];
    const int*   mk = (const int*)d_in[3];   // bool masks pushed as int32
    const float* tw = (const float*)d_in[4];
    const float* dw = (const float*)d_in[5];
    const float* hw = (const float*)d_in[6];
    float*    out = (float*)d_out;
    float*    wsf = (float*)d_ws;
    unsigned* wsi = (unsigned*)d_ws;
    char*     wsb = (char*)d_ws;

    int useY = (ws_size >= NEED_BYTES) ? 1 : 0;
    if (!useY)  // fallback path accumulates into XC with atomics -> needs zeroed XC
        hipMemsetAsync(wsb, 0, (size_t)262144 * 4, stream);

    k_hist1<<<dim3(NB), dim3(256), 0, stream>>>(tc, dc, mk, wsi);
    k_scan_all<<<dim3(1), dim3(1024), 0, stream>>>(wsi);
    k_scatter<<<dim3(NB), dim3(256), 0, stream>>>(tc, dc, mk, wsi, useY);
    k_phaseA<<<dim3(NS, 16), dim3(256), 0, stream>>>(x, tw, wsi, wsf);
    k_phaseB<<<dim3(NS, 16), dim3(256), 0, stream>>>(dw, wsi, wsf, useY);
    if (useY) k_reduce<<<dim3(2048), dim3(128), 0, stream>>>(wsi, wsf);
    k_recur<<<dim3(16), dim3(256), 0, stream>>>(hw, wsf, out);
}